// Round 2
// baseline (32241.245 us; speedup 1.0000x reference)
//
#include <hip/hip_runtime.h>
#include <hip/hip_bf16.h>
#include <cstdint>

// Problem constants: B=32, T=512, N_IN=64, H=512
#define BB 32
#define TT 512
#define NIN 64
#define HH 512
#define G4 2048            // 4*H
#define BH (BB*HH)         // 16384
#define BG (BB*G4)         // 65536

typedef _Float16 h16;
typedef _Float16 half4v __attribute__((ext_vector_type(4)));

__device__ __forceinline__ float4 ld4f(const float* p) { return *(const float4*)p; }
__device__ __forceinline__ float4 ld4f(const h16* p) {
    half4v v = *(const half4v*)p;
    return float4{(float)v[0], (float)v[1], (float)v[2], (float)v[3]};
}
__device__ __forceinline__ void st1(float* p, float v) { *p = v; }
__device__ __forceinline__ void st1(h16* p, float v) { *p = (h16)v; }

// ---------------------------------------------------------------------------
// Transpose [R][C] -> [C][R] fp32 (R,C multiples of 32)
// ---------------------------------------------------------------------------
__global__ void transpose_k(const float* __restrict__ in, float* __restrict__ out,
                            int R, int C) {
    __shared__ float t[32][33];
    int bx = blockIdx.x, by = blockIdx.y;
    int x = threadIdx.x, y = threadIdx.y;  // 32 x 8
    for (int i = 0; i < 32; i += 8)
        t[y + i][x] = in[(size_t)(by * 32 + y + i) * C + bx * 32 + x];
    __syncthreads();
    for (int i = 0; i < 32; i += 8)
        out[(size_t)(bx * 32 + y + i) * R + by * 32 + x] = t[x][y + i];
}

// x [B][T][NIN] -> xt [T][B][NIN]
__global__ void permute_x_k(const float* __restrict__ x, float* __restrict__ xt) {
    int idx = blockIdx.x * 256 + threadIdx.x;       // over T*B*16 float4s
    int q = idx & 15, bt = idx >> 4;                // bt = t*32 + b
    int t = bt >> 5, b = bt & 31;
    ((float4*)xt)[idx] = ((const float4*)x)[((size_t)b * TT + t) * 16 + q];
}

// ---------------------------------------------------------------------------
// C[M][N] = A[M][K] @ B[K][N] (+bias1[n]+bias2[n]); A,B row-major, B fp32.
// out_mode 0: C + m*N.  out_mode 1: row m=(t*32+b) scatters to C+((b*T+t))*N.
// ---------------------------------------------------------------------------
#define GBM 128
#define GBN 64
#define GBK 32
template <typename AT, typename CT>
__global__ __launch_bounds__(256) void gemm_k(
    const AT* __restrict__ A, const float* __restrict__ B,
    CT* __restrict__ C, int M, int N, int K,
    const float* __restrict__ bias1, const float* __restrict__ bias2,
    int out_mode) {
    __shared__ float As[GBM][GBK + 4];
    __shared__ float Bs[GBK][GBN + 4];
    int bm = blockIdx.x, bn = blockIdx.y;
    int tid = threadIdx.x;
    int tx = tid & 15, ty = tid >> 4;
    const AT* Ab = A + (size_t)bm * GBM * K;
    const float* Bb = B + (size_t)bn * GBN;
    float acc[8][4];
#pragma unroll
    for (int i = 0; i < 8; ++i)
#pragma unroll
        for (int j = 0; j < 4; ++j) acc[i][j] = 0.f;

    for (int k0 = 0; k0 < K; k0 += GBK) {
#pragma unroll
        for (int l = 0; l < 4; ++l) {
            int idx = l * 256 + tid;          // 0..1023
            int r = idx >> 3, c4 = idx & 7;   // 128 rows x 8 groups
            *(float4*)&As[r][c4 * 4] = ld4f(Ab + (size_t)r * K + k0 + c4 * 4);
        }
#pragma unroll
        for (int l = 0; l < 2; ++l) {
            int idx = l * 256 + tid;          // 0..511
            int r = idx >> 4, c4 = idx & 15;  // 32 rows x 16 groups
            *(float4*)&Bs[r][c4 * 4] = *(const float4*)(Bb + (size_t)(k0 + r) * N + c4 * 4);
        }
        __syncthreads();
#pragma unroll
        for (int k = 0; k < GBK; ++k) {
            float a[8];
#pragma unroll
            for (int i = 0; i < 8; ++i) a[i] = As[ty * 8 + i][k];
            float4 b4 = *(float4*)&Bs[k][tx * 4];
            float bbv[4] = {b4.x, b4.y, b4.z, b4.w};
#pragma unroll
            for (int i = 0; i < 8; ++i)
#pragma unroll
                for (int j = 0; j < 4; ++j) acc[i][j] += a[i] * bbv[j];
        }
        __syncthreads();
    }
    float badd[4];
#pragma unroll
    for (int j = 0; j < 4; ++j) {
        int n = bn * GBN + tx * 4 + j;
        badd[j] = (bias1 ? bias1[n] : 0.f) + (bias2 ? bias2[n] : 0.f);
    }
#pragma unroll
    for (int i = 0; i < 8; ++i) {
        int m = bm * GBM + ty * 8 + i;
        CT* Crow;
        if (out_mode == 0) Crow = C + (size_t)m * N;
        else               Crow = C + ((size_t)(m & 31) * TT + (m >> 5)) * N;
#pragma unroll
        for (int j = 0; j < 4; ++j)
            st1(&Crow[bn * GBN + tx * 4 + j], acc[i][j] + badd[j]);
    }
}

// ---------------------------------------------------------------------------
// Forward LSTM step. grid 256 WGs x 256 thr. WG w owns cols {2w,2w+1} of each
// gate. g[b,row] = xg[b,row] + sum_k h_prev[b,k]*W_hh[row,k]; pointwise;
// gates (post-act) overwrite xg slab (fp16); c,h carried fp32 + fp16 history.
// ---------------------------------------------------------------------------
#define CK 256
__global__ __launch_bounds__(256) void fwd_step_k(
    const float* __restrict__ W_hh,     // [2048][512]
    h16* __restrict__ xg_t,             // [B][4H]: in xg, out gates
    const float* __restrict__ h_prev,   // [B][H] fp32 or null (t==0)
    float* __restrict__ h_out,          // [B][H] fp32
    const float* __restrict__ c_prev,   // [B][H] fp32 or null
    float* __restrict__ c_out,          // [B][H] fp32
    h16* __restrict__ c_hist,           // [B][H] fp16 history
    h16* __restrict__ h_hist) {         // [B][H] fp16 history or null (layer1)
    __shared__ float in_s[32][CK + 4];
    __shared__ float w_s[8][CK + 4];
    __shared__ float g_s[8][33];
    int tid = threadIdx.x;
    int j0 = blockIdx.x * 2;
    int r = tid >> 5, b = tid & 31;
    int row = (r >> 1) * HH + j0 + (r & 1);
    float acc = (float)xg_t[b * G4 + row];
    if (h_prev) {
        for (int kc = 0; kc < HH; kc += CK) {
#pragma unroll
            for (int l = 0; l < 8; ++l) {               // 32x256 floats
                int idx = l * 256 + tid;
                int rr = idx >> 6, c4 = idx & 63;
                *(float4*)&in_s[rr][c4 * 4] =
                    *(const float4*)(h_prev + rr * HH + kc + c4 * 4);
            }
#pragma unroll
            for (int l = 0; l < 2; ++l) {               // 8x256 floats
                int idx = l * 256 + tid;
                int rr = idx >> 6, c4 = idx & 63;
                int grow = (rr >> 1) * HH + j0 + (rr & 1);
                *(float4*)&w_s[rr][c4 * 4] =
                    *(const float4*)(W_hh + (size_t)grow * HH + kc + c4 * 4);
            }
            __syncthreads();
            float4 s = {0.f, 0.f, 0.f, 0.f};
#pragma unroll 16
            for (int k4 = 0; k4 < CK / 4; ++k4) {
                float4 iv = *(float4*)&in_s[b][k4 * 4];
                float4 wv = *(float4*)&w_s[r][k4 * 4];
                s.x += iv.x * wv.x; s.y += iv.y * wv.y;
                s.z += iv.z * wv.z; s.w += iv.w * wv.w;
            }
            acc += (s.x + s.y) + (s.z + s.w);
            __syncthreads();
        }
    }
    g_s[r][b] = acc;
    __syncthreads();
    if (tid < 64) {
        int jj = tid >> 5, bb = tid & 31;
        int j = j0 + jj;
        float gi = g_s[0 + jj][bb], gf = g_s[2 + jj][bb];
        float gg = g_s[4 + jj][bb], go = g_s[6 + jj][bb];
        float i_ = 1.f / (1.f + expf(-gi));
        float f_ = 1.f / (1.f + expf(-gf));
        float g_ = tanhf(gg);
        float o_ = 1.f / (1.f + expf(-go));
        float cp = c_prev ? c_prev[bb * HH + j] : 0.f;
        float c = f_ * cp + i_ * g_;
        float h = o_ * tanhf(c);
        xg_t[bb * G4 + j]          = (h16)i_;
        xg_t[bb * G4 + HH + j]     = (h16)f_;
        xg_t[bb * G4 + 2 * HH + j] = (h16)g_;
        xg_t[bb * G4 + 3 * HH + j] = (h16)o_;
        c_out[bb * HH + j] = c;
        h_out[bb * HH + j] = h;
        c_hist[bb * HH + j] = (h16)c;
        if (h_hist) h_hist[bb * HH + j] = (h16)h;
    }
}

// ---------------------------------------------------------------------------
// Backward LSTM step, matmul(s) + fused pointwise. grid 128 WGs x 128 thr.
// WG owns j in {4w..4w+3}.  dh[b,j] = [a] sum_gc dG_a[b,gc]*Wt_a[j,gc]
//                                   + [b] sum_gc dG_b[b,gc]*Wt_b[j,gc]
//                                   + [row] dh_ext_row[j]
// Pair a: own-layer recurrence (null at t=T-1). Pair b: layer0's ext from
// layer1 (dG1_t @ W_ih1). Writes dG over gates_t (fp16), dc into dcb (fp32).
// ---------------------------------------------------------------------------
__device__ __forceinline__ float bwd_dot(
    const h16* __restrict__ dG, const float* __restrict__ Wt,
    int j0, int jl, int b, int tid,
    float (*in_s)[CK + 4], float (*w_s)[CK + 4]) {
    float acc = 0.f;
    for (int kc = 0; kc < G4; kc += CK) {
#pragma unroll
        for (int l = 0; l < 16; ++l) {              // 32x256 floats
            int idx = l * 128 + tid;
            int rr = idx >> 6, c4 = idx & 63;
            *(float4*)&in_s[rr][c4 * 4] = ld4f(dG + (size_t)rr * G4 + kc + c4 * 4);
        }
#pragma unroll
        for (int l = 0; l < 2; ++l) {               // 4x256 floats
            int idx = l * 128 + tid;
            int rr = idx >> 6, c4 = idx & 63;
            *(float4*)&w_s[rr][c4 * 4] =
                *(const float4*)(Wt + (size_t)(j0 + rr) * G4 + kc + c4 * 4);
        }
        __syncthreads();
        float4 s = {0.f, 0.f, 0.f, 0.f};
#pragma unroll 16
        for (int k4 = 0; k4 < CK / 4; ++k4) {
            float4 iv = *(float4*)&in_s[b][k4 * 4];
            float4 wv = *(float4*)&w_s[jl][k4 * 4];
            s.x += iv.x * wv.x; s.y += iv.y * wv.y;
            s.z += iv.z * wv.z; s.w += iv.w * wv.w;
        }
        acc += (s.x + s.y) + (s.z + s.w);
        __syncthreads();
    }
    return acc;
}

__global__ __launch_bounds__(128) void bwd_step_k(
    const float* __restrict__ Wt_a,        // [512][2048] own W_hh^T
    const h16* __restrict__ dG_a,          // [B][4H] or null (t==T-1)
    const float* __restrict__ Wt_b,        // [512][2048] W_ih1^T or null
    const h16* __restrict__ dG_b,          // [B][4H] dG1_t or null
    h16* __restrict__ gates_t,             // [B][4H]: read gates, write dG
    const h16* __restrict__ c_t,           // [B][H]
    const h16* __restrict__ c_prev,        // [B][H] or null (t==0)
    float* __restrict__ dcb,               // [B][H] fp32 in/out
    const float* __restrict__ dh_ext_row)  // W_out [H] (layer1) or null
{
    __shared__ float in_s[32][CK + 4];
    __shared__ float w_s[4][CK + 4];
    int tid = threadIdx.x;   // 0..127
    int j0 = blockIdx.x * 4;
    int jl = tid >> 5, b = tid & 31;
    int j = j0 + jl;
    float dh = 0.f;
    if (dG_a) dh += bwd_dot(dG_a, Wt_a, j0, jl, b, tid, in_s, w_s);
    if (dG_b) dh += bwd_dot(dG_b, Wt_b, j0, jl, b, tid, in_s, w_s);
    if (dh_ext_row) dh += dh_ext_row[j];
    float dc_in = dG_a ? dcb[b * HH + j] : 0.f;
    float i_ = (float)gates_t[b * G4 + j];
    float f_ = (float)gates_t[b * G4 + HH + j];
    float g_ = (float)gates_t[b * G4 + 2 * HH + j];
    float o_ = (float)gates_t[b * G4 + 3 * HH + j];
    float c = (float)c_t[b * HH + j];
    float cp = c_prev ? (float)c_prev[b * HH + j] : 0.f;
    float th = tanhf(c);
    float do_ = dh * th;
    float dc = dc_in + dh * o_ * (1.f - th * th);
    float di = dc * g_;
    float df = dc * cp;
    float dg = dc * i_;
    gates_t[b * G4 + j]          = (h16)(di * i_ * (1.f - i_));
    gates_t[b * G4 + HH + j]     = (h16)(df * f_ * (1.f - f_));
    gates_t[b * G4 + 2 * HH + j] = (h16)(dg * (1.f - g_ * g_));
    gates_t[b * G4 + 3 * HH + j] = (h16)(do_ * o_ * (1.f - o_));
    dcb[b * HH + j] = dc * f_;
}

// ---------------------------------------------------------------------------
extern "C" void kernel_launch(void* const* d_in, const int* in_sizes, int n_in,
                              void* d_out, int out_size, void* d_ws, size_t ws_size,
                              hipStream_t stream) {
    const float* x     = (const float*)d_in[0];
    const float* W_ih0 = (const float*)d_in[1];
    const float* W_hh0 = (const float*)d_in[2];
    const float* b_ih0 = (const float*)d_in[3];
    const float* b_hh0 = (const float*)d_in[4];
    const float* W_ih1 = (const float*)d_in[5];
    const float* W_hh1 = (const float*)d_in[6];
    const float* b_ih1 = (const float*)d_in[7];
    const float* b_hh1 = (const float*)d_in[8];
    const float* W_out = (const float*)d_in[9];
    float* out = (float*)d_out;

    // ---- workspace layout (~203 MB) ----
    char* p = (char*)d_ws;
    auto alloc = [&](size_t bytes) { char* r = p; p += (bytes + 255) & ~(size_t)255; return r; };
    h16*  G0    = (h16*)alloc((size_t)TT * BG * 2);   // xg0 -> gates0 -> dG0
    h16*  G1    = (h16*)alloc((size_t)TT * BG * 2);   // xg1 -> gates1 -> dG1
    h16*  C0h   = (h16*)alloc((size_t)TT * BH * 2);
    h16*  C1h   = (h16*)alloc((size_t)TT * BH * 2);
    h16*  H0h   = (h16*)alloc((size_t)TT * BH * 2);
    float* XT     = (float*)alloc((size_t)TT * BB * NIN * 4);
    float* WT_IH0 = (float*)alloc((size_t)NIN * G4 * 4);
    float* WT_IH1 = (float*)alloc((size_t)HH * G4 * 4);
    float* WT_HH0 = (float*)alloc((size_t)HH * G4 * 4);
    float* WT_HH1 = (float*)alloc((size_t)HH * G4 * 4);
    float* HP0[2] = {(float*)alloc(BH * 4), (float*)alloc(BH * 4)};
    float* CP0[2] = {(float*)alloc(BH * 4), (float*)alloc(BH * 4)};
    float* HP1[2] = {(float*)alloc(BH * 4), (float*)alloc(BH * 4)};
    float* CP1[2] = {(float*)alloc(BH * 4), (float*)alloc(BH * 4)};
    float* DCB0   = (float*)alloc(BH * 4);
    float* DCB1   = (float*)alloc(BH * 4);
    if ((size_t)(p - (char*)d_ws) > ws_size) return;  // insufficient workspace

    dim3 tb(32, 8);
    permute_x_k<<<1024, 256, 0, stream>>>(x, XT);
    transpose_k<<<dim3(NIN / 32, G4 / 32), tb, 0, stream>>>(W_ih0, WT_IH0, G4, NIN);
    transpose_k<<<dim3(HH / 32, G4 / 32), tb, 0, stream>>>(W_ih1, WT_IH1, G4, HH);
    transpose_k<<<dim3(HH / 32, G4 / 32), tb, 0, stream>>>(W_hh0, WT_HH0, G4, HH);
    transpose_k<<<dim3(HH / 32, G4 / 32), tb, 0, stream>>>(W_hh1, WT_HH1, G4, HH);

    // xg0 = XT @ W_ih0^T + b_ih0 + b_hh0   [16384 x 2048], K=64  (out fp16)
    gemm_k<float, h16><<<dim3(TT * BB / GBM, G4 / GBN), 256, 0, stream>>>(
        XT, WT_IH0, G0, TT * BB, G4, NIN, b_ih0, b_hh0, 0);

    for (int t = 0; t < TT; ++t)
        fwd_step_k<<<256, 256, 0, stream>>>(
            W_hh0, G0 + (size_t)t * BG,
            t ? HP0[(t + 1) & 1] : nullptr, HP0[t & 1],
            t ? CP0[(t + 1) & 1] : nullptr, CP0[t & 1],
            C0h + (size_t)t * BH, H0h + (size_t)t * BH);

    // xg1 = H0h @ W_ih1^T + b_ih1 + b_hh1  [16384 x 2048], K=512 (A fp16, out fp16)
    gemm_k<h16, h16><<<dim3(TT * BB / GBM, G4 / GBN), 256, 0, stream>>>(
        H0h, WT_IH1, G1, TT * BB, G4, HH, b_ih1, b_hh1, 0);

    for (int t = 0; t < TT; ++t)
        fwd_step_k<<<256, 256, 0, stream>>>(
            W_hh1, G1 + (size_t)t * BG,
            t ? HP1[(t + 1) & 1] : nullptr, HP1[t & 1],
            t ? CP1[(t + 1) & 1] : nullptr, CP1[t & 1],
            C1h + (size_t)t * BH, nullptr);

    // interleaved backward: bwd1(t) then bwd0(t) (bwd0 fuses dG1_t @ W_ih1)
    for (int t = TT - 1; t >= 0; --t) {
        bwd_step_k<<<128, 128, 0, stream>>>(
            WT_HH1, (t < TT - 1) ? G1 + (size_t)(t + 1) * BG : nullptr,
            nullptr, nullptr,
            G1 + (size_t)t * BG,
            C1h + (size_t)t * BH, t ? C1h + (size_t)(t - 1) * BH : nullptr,
            DCB1, W_out);
        bwd_step_k<<<128, 128, 0, stream>>>(
            WT_HH0, (t < TT - 1) ? G0 + (size_t)(t + 1) * BG : nullptr,
            WT_IH1, G1 + (size_t)t * BG,
            G0 + (size_t)t * BG,
            C0h + (size_t)t * BH, t ? C0h + (size_t)(t - 1) * BH : nullptr,
            DCB0, nullptr);
    }

    // dx = dG0 @ W_ih0  [16384 x 64], K=2048 -> scatter to out [B][T][NIN]
    gemm_k<h16, float><<<dim3(TT * BB / GBM, NIN / GBN), 256, 0, stream>>>(
        G0, W_ih0, out, TT * BB, NIN, G4, nullptr, nullptr, 1);
}